// Round 6
// baseline (8039.493 us; speedup 1.0000x reference)
//
#include <hip/hip_runtime.h>
#include <math.h>

#define NCH   64
#define IMW   512
#define NPTS  150000
#define TOTAL (2 * NPTS)
#define IMHW  (512 * 512)
#define HID   32
#define NBINS 32768   // 2 batches x 512 y x 32 x-cells (16 px = one 64B line)

// LDS weight layout (floats): [0..4191] W1 rows 0..130 | [4192..4223] b1
//                             [4224..4319] W2 | [4320..4322] b2
#define WL_B1 4192
#define WL_W2 4224
#define WL_B2 4320
#define WL_SZ 4324

// ---------- sort pass ----------

__global__ __launch_bounds__(256) void hist_kernel(const int* __restrict__ coords,
                                                   int* __restrict__ hist) {
    int gid = blockIdx.x * blockDim.x + threadIdx.x;
    if (gid >= TOTAL) return;
    const int y = coords[gid * 3 + 1];
    const int x = coords[gid * 3 + 2];
    const int b = (gid >= NPTS) ? 1 : 0;
    const int key = (b << 14) | (y << 5) | (x >> 4);
    atomicAdd(&hist[key], 1);
}

__global__ __launch_bounds__(1024) void scan_kernel(const int* __restrict__ hist,
                                                    int* __restrict__ binPos) {
    __shared__ int lds[1024];
    const int t = threadIdx.x;
    const int base = t * 32;
    int loc[32];
    int s = 0;
    #pragma unroll
    for (int i = 0; i < 32; ++i) { loc[i] = s; s += hist[base + i]; }
    lds[t] = s;
    __syncthreads();
    for (int d = 1; d < 1024; d <<= 1) {
        int v = lds[t];
        int add = (t >= d) ? lds[t - d] : 0;
        __syncthreads();
        lds[t] = v + add;
        __syncthreads();
    }
    const int excl = lds[t] - s;
    #pragma unroll
    for (int i = 0; i < 32; ++i) binPos[base + i] = excl + loc[i];
}

__global__ __launch_bounds__(256) void scatter_kernel(const int* __restrict__ coords,
                                                      int* __restrict__ binPos,
                                                      int* __restrict__ perm) {
    int gid = blockIdx.x * blockDim.x + threadIdx.x;
    if (gid >= TOTAL) return;
    const int y = coords[gid * 3 + 1];
    const int x = coords[gid * 3 + 2];
    const int b = (gid >= NPTS) ? 1 : 0;
    const int key = (b << 14) | (y << 5) | (x >> 4);
    const int pos = atomicAdd(&binPos[key], 1);
    perm[pos] = gid;
}

// ---------- fused gather + MLP, LDS weights + pipelined gathers ----------

#define LOADCH(buf, ptr, cbase)                                            \
    _Pragma("unroll")                                                      \
    for (int j = 0; j < 16; ++j) buf[j] = (ptr)[(long)((cbase) + j) * IMHW];

#define FMACH(buf, rbase)                                                  \
    _Pragma("unroll")                                                      \
    for (int j = 0; j < 16; ++j) {                                         \
        const float* wr = &wl[((rbase) + j) * HID];                        \
        _Pragma("unroll")                                                  \
        for (int h = 0; h < HID; ++h) acc[h] = fmaf(buf[j], wr[h], acc[h]); \
    }

#define SB __builtin_amdgcn_sched_barrier(0);

__global__ __launch_bounds__(256) void ffd_kernel(
    const float* __restrict__ before,
    const float* __restrict__ after,
    const float* __restrict__ offsets,
    const int*   __restrict__ coords,
    const float* __restrict__ W1,   // [131, 32]
    const float* __restrict__ b1,   // [32]
    const float* __restrict__ W2,   // [32, 3]
    const float* __restrict__ b2,   // [3]
    const int*   __restrict__ perm, // sorted point order (or null)
    float*       __restrict__ out)  // [2, 150000, 3]
{
    __shared__ float wl[WL_SZ];

    // stage all weights into LDS (broadcast-read later; conflict-free)
    for (int i = threadIdx.x; i < 131 * HID; i += 256) wl[i] = W1[i];
    if (threadIdx.x < HID) wl[WL_B1 + threadIdx.x] = b1[threadIdx.x];
    if (threadIdx.x < 96)  wl[WL_W2 + threadIdx.x] = W2[threadIdx.x];
    if (threadIdx.x < 3)   wl[WL_B2 + threadIdx.x] = b2[threadIdx.x];
    __syncthreads();

    int gpt = blockIdx.x * blockDim.x + threadIdx.x;
    const bool valid = gpt < TOTAL;
    if (!valid) gpt = TOTAL - 1;           // clamp: compute garbage, don't store

    const int pid = perm ? perm[gpt] : gpt;
    const long pbase = (long)pid * 3;

    const int y = coords[pbase + 1];
    const int x = coords[pbase + 2];
    const int b = (pid >= NPTS) ? 1 : 0;

    const long img_off = (long)b * NCH * IMHW + (long)y * IMW + x;
    const float* bp = before + img_off;
    const float* ap = after  + img_off;

    // prologue: two chunks in flight before any compute
    float ga[16], gb[16];
    LOADCH(ga, bp, 0)
    LOADCH(gb, bp, 16)
    SB

    // init acc with bias + offsets rows (done while chunks fly)
    float acc[HID];
    {
        const float o0 = offsets[pbase + 0];
        const float o1 = offsets[pbase + 1];
        const float o2 = offsets[pbase + 2];
        const float* r0 = &wl[128 * HID];
        const float* r1 = &wl[129 * HID];
        const float* r2 = &wl[130 * HID];
        #pragma unroll
        for (int h = 0; h < HID; ++h)
            acc[h] = fmaf(o2, r2[h], fmaf(o1, r1[h], fmaf(o0, r0[h], wl[WL_B1 + h])));
    }
    SB

    FMACH(ga, 0)   LOADCH(ga, bp, 32)  SB    // consume c0, fetch c2
    FMACH(gb, 16)  LOADCH(gb, bp, 48)  SB
    FMACH(ga, 32)  LOADCH(ga, ap, 0)   SB    // rows 64..79
    FMACH(gb, 48)  LOADCH(gb, ap, 16)  SB
    FMACH(ga, 64)  LOADCH(ga, ap, 32)  SB
    FMACH(gb, 80)  LOADCH(gb, ap, 48)  SB
    FMACH(ga, 96)
    FMACH(gb, 112)

    // epilogue: GELU + W2
    #pragma unroll
    for (int h = 0; h < HID; ++h) {
        const float xh = acc[h];
        acc[h] = 0.5f * xh * (1.0f + erff(xh * 0.70710678118654752f));
    }

    float q0 = wl[WL_B2 + 0], q1 = wl[WL_B2 + 1], q2 = wl[WL_B2 + 2];
    #pragma unroll
    for (int h = 0; h < HID; ++h) {
        q0 = fmaf(acc[h], wl[WL_W2 + h * 3 + 0], q0);
        q1 = fmaf(acc[h], wl[WL_W2 + h * 3 + 1], q1);
        q2 = fmaf(acc[h], wl[WL_W2 + h * 3 + 2], q2);
    }

    if (valid) {
        out[pbase + 0] = q0;
        out[pbase + 1] = q1;
        out[pbase + 2] = q2;
    }
}

extern "C" void kernel_launch(void* const* d_in, const int* in_sizes, int n_in,
                              void* d_out, int out_size, void* d_ws, size_t ws_size,
                              hipStream_t stream) {
    const float* before  = (const float*)d_in[0];
    const float* after   = (const float*)d_in[1];
    const float* offsets = (const float*)d_in[2];
    const int*   coords  = (const int*)  d_in[3];
    const float* W1      = (const float*)d_in[4];
    const float* b1      = (const float*)d_in[5];
    const float* W2      = (const float*)d_in[6];
    const float* b2      = (const float*)d_in[7];
    float* out = (float*)d_out;

    const int block = 256;
    const int grid  = (TOTAL + block - 1) / block;

    // ws layout: hist[NBINS] | binPos[NBINS] | perm[TOTAL]
    const size_t need = (size_t)(2 * NBINS + TOTAL) * sizeof(int);

    if (ws_size >= need) {
        int* hist   = (int*)d_ws;
        int* binPos = hist + NBINS;
        int* perm   = binPos + NBINS;

        hipMemsetAsync(hist, 0, NBINS * sizeof(int), stream);
        hist_kernel<<<grid, block, 0, stream>>>(coords, hist);
        scan_kernel<<<1, 1024, 0, stream>>>(hist, binPos);
        scatter_kernel<<<grid, block, 0, stream>>>(coords, binPos, perm);
        ffd_kernel<<<grid, block, 0, stream>>>(before, after, offsets, coords,
                                               W1, b1, W2, b2, perm, out);
    } else {
        ffd_kernel<<<grid, block, 0, stream>>>(before, after, offsets, coords,
                                               W1, b1, W2, b2, nullptr, out);
    }
}

// Round 7
// 120.686 us; speedup vs baseline: 66.6149x; 66.6149x over previous
//
#include <hip/hip_runtime.h>
#include <math.h>

#define NCH   64
#define IMW   512
#define NPTS  150000
#define TOTAL (2 * NPTS)
#define IMHW  (512 * 512)
#define HID   32
#define NBINS 32768   // 2 batches x 512 y x 32 x-cells (16 px = one 64B line)

// LDS weight layout (floats): [0..4191] W1 rows 0..130 | [4192..4223] b1
//                             [4224..4319] W2 | [4320..4322] b2
#define WL_B1 4192
#define WL_W2 4224
#define WL_B2 4320
#define WL_SZ 4324

// ---------- sort pass ----------

__global__ __launch_bounds__(256) void hist_kernel(const int* __restrict__ coords,
                                                   int* __restrict__ hist) {
    int gid = blockIdx.x * blockDim.x + threadIdx.x;
    if (gid >= TOTAL) return;
    const int y = coords[gid * 3 + 1];
    const int x = coords[gid * 3 + 2];
    const int b = (gid >= NPTS) ? 1 : 0;
    const int key = (b << 14) | (y << 5) | (x >> 4);
    atomicAdd(&hist[key], 1);
}

__global__ __launch_bounds__(1024) void scan_kernel(const int* __restrict__ hist,
                                                    int* __restrict__ binPos) {
    __shared__ int lds[1024];
    const int t = threadIdx.x;
    const int base = t * 32;
    int loc[32];
    int s = 0;
    #pragma unroll
    for (int i = 0; i < 32; ++i) { loc[i] = s; s += hist[base + i]; }
    lds[t] = s;
    __syncthreads();
    for (int d = 1; d < 1024; d <<= 1) {
        int v = lds[t];
        int add = (t >= d) ? lds[t - d] : 0;
        __syncthreads();
        lds[t] = v + add;
        __syncthreads();
    }
    const int excl = lds[t] - s;
    #pragma unroll
    for (int i = 0; i < 32; ++i) binPos[base + i] = excl + loc[i];
}

__global__ __launch_bounds__(256) void scatter_kernel(const int* __restrict__ coords,
                                                      int* __restrict__ binPos,
                                                      int* __restrict__ perm) {
    int gid = blockIdx.x * blockDim.x + threadIdx.x;
    if (gid >= TOTAL) return;
    const int y = coords[gid * 3 + 1];
    const int x = coords[gid * 3 + 2];
    const int b = (gid >= NPTS) ? 1 : 0;
    const int key = (b << 14) | (y << 5) | (x >> 4);
    const int pos = atomicAdd(&binPos[key], 1);
    perm[pos] = gid;
}

// ---------- fused gather + MLP, weights in LDS, compiler-scheduled ----------

__global__ __launch_bounds__(256) void ffd_kernel(
    const float* __restrict__ before,
    const float* __restrict__ after,
    const float* __restrict__ offsets,
    const int*   __restrict__ coords,
    const float* __restrict__ W1,   // [131, 32]
    const float* __restrict__ b1,   // [32]
    const float* __restrict__ W2,   // [32, 3]
    const float* __restrict__ b2,   // [3]
    const int*   __restrict__ perm, // sorted point order (or null)
    float*       __restrict__ out)  // [2, 150000, 3]
{
    __shared__ float wl[WL_SZ];

    // stage all weights into LDS (read as all-lanes-same-address broadcasts
    // later -> conflict-free, ds_read_b128-vectorizable)
    for (int i = threadIdx.x; i < 131 * HID; i += 256) wl[i] = W1[i];
    if (threadIdx.x < HID) wl[WL_B1 + threadIdx.x] = b1[threadIdx.x];
    if (threadIdx.x < 96)  wl[WL_W2 + threadIdx.x] = W2[threadIdx.x];
    if (threadIdx.x < 3)   wl[WL_B2 + threadIdx.x] = b2[threadIdx.x];
    __syncthreads();

    int gpt = blockIdx.x * blockDim.x + threadIdx.x;
    const bool valid = gpt < TOTAL;
    if (!valid) gpt = TOTAL - 1;           // clamp: compute garbage, don't store

    const int pid = perm ? perm[gpt] : gpt;
    const long pbase = (long)pid * 3;

    const int y = coords[pbase + 1];
    const int x = coords[pbase + 2];
    const int b = (pid >= NPTS) ? 1 : 0;

    const long img_off = (long)b * NCH * IMHW + (long)y * IMW + x;
    const float* bp = before + img_off;
    const float* ap = after  + img_off;

    // init acc with bias + offsets rows
    float acc[HID];
    {
        const float o0 = offsets[pbase + 0];
        const float o1 = offsets[pbase + 1];
        const float o2 = offsets[pbase + 2];
        const float* r0 = &wl[128 * HID];
        const float* r1 = &wl[129 * HID];
        const float* r2 = &wl[130 * HID];
        #pragma unroll
        for (int h = 0; h < HID; ++h)
            acc[h] = fmaf(o2, r2[h], fmaf(o1, r1[h], fmaf(o0, r0[h], wl[WL_B1 + h])));
    }

    float g[16];

    // before image: W1 rows 0..63
    for (int cc = 0; cc < NCH; cc += 16) {
        #pragma unroll
        for (int j = 0; j < 16; ++j) g[j] = bp[(long)(cc + j) * IMHW];
        #pragma unroll
        for (int j = 0; j < 16; ++j) {
            const float* wr = &wl[(cc + j) * HID];
            #pragma unroll
            for (int h = 0; h < HID; ++h) acc[h] = fmaf(g[j], wr[h], acc[h]);
        }
    }
    // after image: W1 rows 64..127
    for (int cc = 0; cc < NCH; cc += 16) {
        #pragma unroll
        for (int j = 0; j < 16; ++j) g[j] = ap[(long)(cc + j) * IMHW];
        #pragma unroll
        for (int j = 0; j < 16; ++j) {
            const float* wr = &wl[(64 + cc + j) * HID];
            #pragma unroll
            for (int h = 0; h < HID; ++h) acc[h] = fmaf(g[j], wr[h], acc[h]);
        }
    }

    // epilogue: GELU + W2
    #pragma unroll
    for (int h = 0; h < HID; ++h) {
        const float xh = acc[h];
        acc[h] = 0.5f * xh * (1.0f + erff(xh * 0.70710678118654752f));
    }

    float q0 = wl[WL_B2 + 0], q1 = wl[WL_B2 + 1], q2 = wl[WL_B2 + 2];
    #pragma unroll
    for (int h = 0; h < HID; ++h) {
        q0 = fmaf(acc[h], wl[WL_W2 + h * 3 + 0], q0);
        q1 = fmaf(acc[h], wl[WL_W2 + h * 3 + 1], q1);
        q2 = fmaf(acc[h], wl[WL_W2 + h * 3 + 2], q2);
    }

    if (valid) {
        out[pbase + 0] = q0;
        out[pbase + 1] = q1;
        out[pbase + 2] = q2;
    }
}

extern "C" void kernel_launch(void* const* d_in, const int* in_sizes, int n_in,
                              void* d_out, int out_size, void* d_ws, size_t ws_size,
                              hipStream_t stream) {
    const float* before  = (const float*)d_in[0];
    const float* after   = (const float*)d_in[1];
    const float* offsets = (const float*)d_in[2];
    const int*   coords  = (const int*)  d_in[3];
    const float* W1      = (const float*)d_in[4];
    const float* b1      = (const float*)d_in[5];
    const float* W2      = (const float*)d_in[6];
    const float* b2      = (const float*)d_in[7];
    float* out = (float*)d_out;

    const int block = 256;
    const int grid  = (TOTAL + block - 1) / block;

    // ws layout: hist[NBINS] | binPos[NBINS] | perm[TOTAL]
    const size_t need = (size_t)(2 * NBINS + TOTAL) * sizeof(int);

    if (ws_size >= need) {
        int* hist   = (int*)d_ws;
        int* binPos = hist + NBINS;
        int* perm   = binPos + NBINS;

        hipMemsetAsync(hist, 0, NBINS * sizeof(int), stream);
        hist_kernel<<<grid, block, 0, stream>>>(coords, hist);
        scan_kernel<<<1, 1024, 0, stream>>>(hist, binPos);
        scatter_kernel<<<grid, block, 0, stream>>>(coords, binPos, perm);
        ffd_kernel<<<grid, block, 0, stream>>>(before, after, offsets, coords,
                                               W1, b1, W2, b2, perm, out);
    } else {
        ffd_kernel<<<grid, block, 0, stream>>>(before, after, offsets, coords,
                                               W1, b1, W2, b2, nullptr, out);
    }
}